// Round 6
// baseline (2119.358 us; speedup 1.0000x reference)
//
#include <hip/hip_runtime.h>
#include <cstdint>
#include <cstddef>

#define Vv 32000
#define Ee 512
#define Hh 512
#define Bb 32
#define Ss 128

typedef __bf16 bf16x8 __attribute__((ext_vector_type(8)));
typedef float  f32x4  __attribute__((ext_vector_type(4)));
typedef unsigned long long ull;

__device__ __forceinline__ float b2f(unsigned short u) {
  union { unsigned int i; float f; } v; v.i = ((unsigned int)u) << 16; return v.f;
}
__device__ __forceinline__ unsigned short f2b(float f) {
  union { float f; unsigned int i; } v; v.f = f;
  unsigned int r = v.i + 0x7FFFu + ((v.i >> 16) & 1u);
  return (unsigned short)(r >> 16);
}
__device__ __forceinline__ float sigm(float x) { return 1.f / (1.f + __expf(-x)); }

// Cross-XCD coherent 8B ops (sc1 path through the coherence point).
__device__ __forceinline__ ull aload8(const ull* p) {
  return __hip_atomic_load(p, __ATOMIC_RELAXED, __HIP_MEMORY_SCOPE_AGENT);
}
__device__ __forceinline__ void astore8(ull* p, ull v) {
  __hip_atomic_store(p, v, __ATOMIC_RELAXED, __HIP_MEMORY_SCOPE_AGENT);
}
// strip two tagged u32 words -> packed 2x bf16
__device__ __forceinline__ unsigned pack32(ull v) {
  return (unsigned)(v & 0xFFFFull) | (unsigned)((v >> 16) & 0xFFFF0000ull);
}
__device__ __forceinline__ ull packpair(float a, float b, unsigned tag) {
  ull lo = (ull)((unsigned)f2b(a) | (tag << 16));
  ull hi = (ull)((unsigned)f2b(b) | (tag << 16));
  return lo | (hi << 32);
}

// async global->LDS, 16B per lane
__device__ __forceinline__ void gl_lds16(const unsigned short* g, unsigned short* l) {
  __builtin_amdgcn_global_load_lds(
      (const __attribute__((address_space(1))) void*)g,
      (__attribute__((address_space(3))) void*)l, 16, 0, 0);
}

// ---------------- merged prep kernel ----------------
// blocks [0,1536): cast w_ih0 ; [1536,3072): cast w_hh0 ; [3072,6144): pack_w1 ;
// [6144,8192): embed (2 rows/block) ; 8192: zero flags
__global__ __launch_bounds__(256) void prep_all(
    const float* __restrict__ w_ih0, const float* __restrict__ w_hh0,
    const float* __restrict__ w_ih1, const float* __restrict__ w_hh1,
    const int* __restrict__ target, const float* __restrict__ table,
    unsigned short* __restrict__ wih0b, unsigned short* __restrict__ whh0b,
    unsigned short* __restrict__ w1cat, unsigned short* __restrict__ emb,
    unsigned* __restrict__ bar) {
  int blk = blockIdx.x, t = threadIdx.x;
  if (blk < 1536) {
    int i = blk * 256 + t;
    float4 v = reinterpret_cast<const float4*>(w_ih0)[i];
    ushort4 o; o.x = f2b(v.x); o.y = f2b(v.y); o.z = f2b(v.z); o.w = f2b(v.w);
    reinterpret_cast<ushort4*>(wih0b)[i] = o;
  } else if (blk < 3072) {
    int i = (blk - 1536) * 256 + t;
    float4 v = reinterpret_cast<const float4*>(w_hh0)[i];
    ushort4 o; o.x = f2b(v.x); o.y = f2b(v.y); o.z = f2b(v.z); o.w = f2b(v.w);
    reinterpret_cast<ushort4*>(whh0b)[i] = o;
  } else if (blk < 6144) {
    int r = blk - 3072;  // d*1536 + n
    const float* si = w_ih1 + (size_t)r * 1024;
    const float* sh = w_hh1 + (size_t)r * 512;
    unsigned short* dr = w1cat + (size_t)r * 1536;
    for (int c = t; c < 1024; c += 256) dr[c] = f2b(si[c]);
    for (int c = t; c < 512; c += 256) dr[1024 + c] = f2b(sh[c]);
  } else if (blk < 8192) {
    int sb = (blk - 6144) * 2 + (t >> 7);
    int tt = t & 127;
    int s = sb >> 5, b = sb & 31;
    int tok = target[b * Ss + s];
    float4 v = reinterpret_cast<const float4*>(table + (size_t)tok * Ee)[tt];
    ushort4 o; o.x = f2b(v.x); o.y = f2b(v.y); o.z = f2b(v.z); o.w = f2b(v.w);
    reinterpret_cast<ushort4*>(emb + (size_t)sb * Ee)[tt] = o;
  } else {
    for (int i = t; i < 4096; i += 256) bar[i] = 0u;
  }
}

// ---------------- bf16 MFMA GEMM: C = A * B^T + bias ----------------
template <int MODE>
__global__ __launch_bounds__(256, 2) void gemm_nt(
    const unsigned short* __restrict__ A, const unsigned short* __restrict__ Bm,
    const float* __restrict__ bias, void* __restrict__ Cout,
    int K, int ldc, size_t sBz, size_t sCz, size_t sBiasz,
    float* __restrict__ pm, float* __restrict__ ps) {
  int z = blockIdx.z;
  Bm += z * sBz;
  bias += z * sBiasz;

  __shared__ __align__(16) unsigned short As[128 * 64];
  __shared__ __align__(16) unsigned short Bs[128 * 64];
  __shared__ float smx[128][2], sse[128][2];

  int t = threadIdx.x;
  int bx, by;
  if (MODE == 1) {
    int lin = blockIdx.x + (int)gridDim.x * blockIdx.y;
    int q = (int)(gridDim.x * gridDim.y) >> 3;
    int wg = (lin & 7) * q + (lin >> 3);
    bx = wg & 31; by = wg >> 5;
  } else {
    bx = blockIdx.x; by = blockIdx.y;
  }
  int m0 = bx * 128, n0 = by * 128;
  int wave = t >> 6, lane = t & 63;
  int wr = wave >> 1, wc = wave & 1;

  f32x4 acc[4][4] = {};

  int kt = K >> 6;
  for (int ks = 0; ks < kt; ++ks) {
    int k0 = ks << 6;
#pragma unroll
    for (int c = 0; c < 4; ++c) {
      int v = c * 256 + t;
      int row = v >> 3, col = (v & 7) * 8;
      int vb = (c * 256 + (t & 192)) * 8;
      gl_lds16(A + (size_t)(m0 + row) * K + k0 + col, As + vb);
      gl_lds16(Bm + (size_t)(n0 + row) * K + k0 + col, Bs + vb);
    }
    __syncthreads();
#pragma unroll
    for (int kk = 0; kk < 2; ++kk) {
      bf16x8 af[4], bfr[4];
      int lrow = lane & 15, lk = kk * 32 + (lane >> 4) * 8;
#pragma unroll
      for (int m = 0; m < 4; ++m)
        af[m] = *reinterpret_cast<const bf16x8*>(As + (wr * 64 + m * 16 + lrow) * 64 + lk);
#pragma unroll
      for (int n = 0; n < 4; ++n)
        bfr[n] = *reinterpret_cast<const bf16x8*>(Bs + (wc * 64 + n * 16 + lrow) * 64 + lk);
#pragma unroll
      for (int m = 0; m < 4; ++m)
#pragma unroll
        for (int n = 0; n < 4; ++n)
          acc[m][n] = __builtin_amdgcn_mfma_f32_16x16x32_bf16(af[m], bfr[n], acc[m][n], 0, 0, 0);
    }
    __syncthreads();
  }

  int lrow4 = (lane >> 4) * 4, lcol = lane & 15;
  if (MODE == 0) {
#pragma unroll
    for (int m = 0; m < 4; ++m) {
      int rbase = m0 + wr * 64 + m * 16 + lrow4;
#pragma unroll
      for (int n = 0; n < 4; ++n) {
        int col = n0 + wc * 64 + n * 16 + lcol;
        float bv = bias[col];
#pragma unroll
        for (int j = 0; j < 4; ++j) {
          int r = rbase + j;
          float vv = acc[m][n][j] + bv;
          ((unsigned short*)Cout)[z * sCz + (size_t)r * ldc + col] = f2b(vv);
        }
      }
    }
  } else {
    float bv[4];
#pragma unroll
    for (int n = 0; n < 4; ++n) bv[n] = bias[n0 + wc * 64 + n * 16 + lcol];
#pragma unroll
    for (int m = 0; m < 4; ++m) {
#pragma unroll
      for (int j = 0; j < 4; ++j) {
        float x[4];
#pragma unroll
        for (int n = 0; n < 4; ++n) x[n] = acc[m][n][j] + bv[n];
        int rib = wr * 64 + m * 16 + lrow4 + j;
        int r = m0 + rib;
        int b = r & 31, s = r >> 5;
        float* crow = (float*)Cout + (size_t)(b * Ss + s) * ldc;
#pragma unroll
        for (int n = 0; n < 4; ++n)
          __builtin_nontemporal_store(x[n], crow + n0 + wc * 64 + n * 16 + lcol);
        float mx = fmaxf(fmaxf(x[0], x[1]), fmaxf(x[2], x[3]));
#pragma unroll
        for (int msk = 1; msk < 16; msk <<= 1) mx = fmaxf(mx, __shfl_xor(mx, msk, 16));
        float se = __expf(x[0] - mx) + __expf(x[1] - mx) + __expf(x[2] - mx) + __expf(x[3] - mx);
#pragma unroll
        for (int msk = 1; msk < 16; msk <<= 1) se += __shfl_xor(se, msk, 16);
        if (lcol == 0) { smx[rib][wc] = mx; sse[rib][wc] = se; }
      }
    }
    __syncthreads();
    if (t < 128) {
      float ma = smx[t][0], mb = smx[t][1];
      float M = fmaxf(ma, mb);
      float S = sse[t][0] * __expf(ma - M) + sse[t][1] * __expf(mb - M);
      int rg = m0 + t;
      int b = rg & 31, s = rg >> 5;
      size_t orow = (size_t)(b * Ss + s);
      pm[orow * 250 + by] = M;
      ps[orow * 250 + by] = S;
    }
  }
}

// ---------------- persistent recurrence kernel (tag-in-data sync) ----------------
// grid = 256 blocks x 512 threads. blk<64: layer1; 64<=blk<128: layer0;
// blk>=128: fc_w cast helpers (overlapped, no sync participation).
// State words are u32 = (phase_tag<<16)|bf16. Producers store tagged words
// (relaxed sc1, no drain, no flag); consumers batch-load and poll tags in the
// data. Buffers mod-8. Consumer-progress flags only for slot-reuse
// backpressure, checked every 4 phases (3-phase slack).
// XO: u32[8][32][1024] (h0, col=d*512+j). H1: u32[8][2][32][512].
// Write at phase p: slot p&7, tag p+1. Read at phase p: slot (p-1)&7, tag p.
// Init: h0(-1)->XO slot7 tag0; h1(-1)->H1 slot0 tag1. All other slots scrubbed
// to tag 0xFFFF at start (startup barrier) and at end (replay safety).

#define MFMA16 __builtin_amdgcn_mfma_f32_16x16x32_bf16
#define L1_STRIDE 1544
#define L0_STRIDE 520
#define TAGMASK 0xFFFF0000FFFF0000ull

__global__ __launch_bounds__(512, 1) void pers_kernel(
    const unsigned short* __restrict__ gi0,
    const unsigned short* __restrict__ whh0b, const unsigned short* __restrict__ w1cat,
    const float* __restrict__ b_hh0, const float* __restrict__ b_ih1, const float* __restrict__ b_hh1,
    const float* __restrict__ context,
    unsigned* __restrict__ XO, unsigned* __restrict__ H1,
    unsigned short* __restrict__ outs, unsigned* bar,
    const float* __restrict__ fc_w, unsigned short* __restrict__ fcwb) {
  const int tid = threadIdx.x, blk = blockIdx.x;

  // ---------- cast helpers (overlap fc_w cast under the recurrence) ----------
  if (blk >= 128) {
    int base = (blk - 128) * 512 + tid;
#pragma unroll 5
    for (int i = base; i < 8192000; i += 65536) {
      float4 v = reinterpret_cast<const float4*>(fc_w)[i];
      ushort4 o; o.x = f2b(v.x); o.y = f2b(v.y); o.z = f2b(v.z); o.w = f2b(v.w);
      reinterpret_cast<ushort4*>(fcwb)[i] = o;
    }
    return;
  }

  extern __shared__ __align__(16) unsigned short A_lds[];
  __shared__ float pre[7][16][33];
  __shared__ float hf[32][16];
  __shared__ float bA[16], bB[16], bC[16], bD[16];
  __shared__ unsigned sAbort;

  unsigned* flags = bar;          // flag[i] at bar[i*16] (64B stride)
  unsigned* abortf = bar + 3072;

  const int w = tid >> 6, lane = tid & 63, ln = lane & 15;
  const int hi8 = (lane >> 4) * 8;
  const bool isL1 = blk < 64;
  const int d = (blk & 63) >> 5, j0 = (blk & 31) * 16;
  const int g = w >> 1, kh = w & 1;   // valid for w<6

  if (tid == 0) sAbort = 0u;

  // wave-divergence-safe flag poll (idx<0 lanes are trivially satisfied)
  auto pollwait = [&](int idx, unsigned tgt) {
    ull t0 = __builtin_amdgcn_s_memrealtime();
    while (true) {
      unsigned f = (idx >= 0)
          ? __hip_atomic_load(flags + (size_t)idx * 16, __ATOMIC_RELAXED, __HIP_MEMORY_SCOPE_AGENT)
          : 0xFFFFFFFu;
      if (__all(f >= tgt)) break;
      if ((__builtin_amdgcn_s_memrealtime() - t0) > 100000000ULL ||
          __hip_atomic_load(abortf, __ATOMIC_RELAXED, __HIP_MEMORY_SCOPE_AGENT) != 0u) {
        __hip_atomic_store(abortf, 1u, __ATOMIC_RELAXED, __HIP_MEMORY_SCOPE_AGENT);
        sAbort = 1u;
        break;
      }
      __builtin_amdgcn_s_sleep(1);
    }
  };

  auto stile = [&](int s, f32x4 v0, f32x4 v1) {
    int c = ln, r0 = (lane >> 4) * 4;
#pragma unroll
    for (int j = 0; j < 4; ++j) {
      pre[s][c][r0 + j] = v0[j];
      pre[s][c][16 + r0 + j] = v1[j];
    }
  };

  // ---- weights -> registers (once, MFMA waves only) ----
  bf16x8 wreg[24];
  if (w < 6) {
    if (isL1) {
      const unsigned short* Bw =
          w1cat + ((size_t)d * 1536 + g * 512 + j0 + ln) * 1536 + kh * 768 + hi8;
#pragma unroll
      for (int i = 0; i < 24; ++i) wreg[i] = *reinterpret_cast<const bf16x8*>(Bw + i * 32);
    } else {
      const unsigned short* Bw =
          whh0b + ((size_t)d * 1536 + g * 512 + j0 + ln) * 512 + kh * 256 + hi8;
#pragma unroll
      for (int i = 0; i < 8; ++i) wreg[i] = *reinterpret_cast<const bf16x8*>(Bw + i * 32);
    }
  }

  // ---- biases ----
  if (tid < 16) {
    int jj = tid;
    if (isL1) {
      bA[jj] = b_ih1[d * 1536 + j0 + jj] + b_hh1[d * 1536 + j0 + jj];
      bB[jj] = b_ih1[d * 1536 + 512 + j0 + jj] + b_hh1[d * 1536 + 512 + j0 + jj];
      bC[jj] = b_ih1[d * 1536 + 1024 + j0 + jj];
      bD[jj] = b_hh1[d * 1536 + 1024 + j0 + jj];
    } else {
      bA[jj] = b_hh0[d * 1536 + j0 + jj];
      bB[jj] = b_hh0[d * 1536 + 512 + j0 + jj];
      bC[jj] = b_hh0[d * 1536 + 1024 + j0 + jj];
    }
  }

  // ---- init state + scrub all other slots ----
  if (tid < 128) {
    int b = tid >> 2, j4 = (tid & 3) * 4;
    int layer = isL1 ? 1 : 0;
    float c0 = context[(((size_t)layer * 2 + d) * 32 + b) * 512 + j0 + j4 + 0];
    float c1 = context[(((size_t)layer * 2 + d) * 32 + b) * 512 + j0 + j4 + 1];
    float c2 = context[(((size_t)layer * 2 + d) * 32 + b) * 512 + j0 + j4 + 2];
    float c3 = context[(((size_t)layer * 2 + d) * 32 + b) * 512 + j0 + j4 + 3];
    hf[b][j4 + 0] = c0; hf[b][j4 + 1] = c1; hf[b][j4 + 2] = c2; hf[b][j4 + 3] = c3;
    if (isL1) {
      ull* dst = (ull*)H1 + ((size_t)(0 * 2 + d) * 32 + b) * 256 + ((j0 + j4) >> 1);
      astore8(dst, packpair(c0, c1, 1u));
      astore8(dst + 1, packpair(c2, c3, 1u));
    } else {
      ull* dst = (ull*)XO + ((size_t)(7 * 32 + b)) * 512 + d * 256 + ((j0 + j4) >> 1);
      astore8(dst, packpair(c0, c1, 0u));
      astore8(dst + 1, packpair(c2, c3, 0u));
    }
#pragma unroll
    for (int s = 0; s < 8; ++s) {
      if (isL1 ? (s == 0) : (s == 7)) continue;
      ull* dst = isL1
          ? (ull*)H1 + (((size_t)s * 2 + d) * 32 + b) * 256 + ((j0 + j4) >> 1)
          : (ull*)XO + ((size_t)s * 32 + b) * 512 + d * 256 + ((j0 + j4) >> 1);
      astore8(dst, ~0ull);
      astore8(dst + 1, ~0ull);
    }
  }
  __syncthreads();  // drains init/scrub stores
  if (tid == 0)
    __hip_atomic_store(flags + (size_t)blk * 16, 1u, __ATOMIC_RELAXED, __HIP_MEMORY_SCOPE_AGENT);
  // startup barrier: everyone's scrub done before any tag-poll
  if (w == 6) pollwait(lane, 1u);
  else if (w == 7) pollwait(64 + lane, 1u);
  __syncthreads();
  bool dead = (sAbort != 0u);

  // ---- phase loop ----
  if (!dead) {
    for (int p = 0; p <= 128; ++p) {
      bool l0act = (!isL1) && p <= 127;
      bool l1act = isL1 && p >= 1;
      int s_rd = (p - 1) & 7, s_wr = p & 7;
      ull ex = ((ull)(unsigned)p << 16) | ((ull)(unsigned)p << 48);

      // L0: gi0 prefetch (plain loads, L2-cached)
      ull gr = 0, gz2 = 0, gn2 = 0;
      if (l0act && tid < 128) {
        const unsigned short* gzp =
            gi0 + ((size_t)d * 128 + p) * 32 * 1536 + (size_t)(tid >> 2) * 1536 + j0 + (tid & 3) * 4;
        gr  = *(const ull*)(gzp);
        gz2 = *(const ull*)(gzp + 512);
        gn2 = *(const ull*)(gzp + 1024);
      }

      // amortized backpressure (slot reuse safety), every 4 phases
      if ((p & 3) == 0 && p >= 4) {
        if (isL1) {
          if (w == 6) pollwait(lane < 32 ? d * 32 + lane : -1, (unsigned)(p - 2));
        } else if (p <= 127) {
          if (w == 6) pollwait(lane, (unsigned)(p - 2));
          else if (w == 7) pollwait(lane < 32 ? 64 + d * 32 + lane : -1, (unsigned)(p - 2));
        }
      }

      // ---- stage with tag-poll ----
      if (l1act) {
        const ull* xw = (const ull*)XO + (size_t)s_rd * 16384;
        const ull* hw = (const ull*)H1 + ((size_t)s_rd * 2 + d) * 8192;
        ull vx[32], vh[16];
#pragma unroll
        for (int k = 0; k < 32; ++k) vx[k] = aload8(xw + tid + k * 512);
#pragma unroll
        for (int k = 0; k < 16; ++k) vh[k] = aload8(hw + tid + k * 512);
        unsigned pendA = 0, pendB = 0;
#pragma unroll
        for (int k = 0; k < 32; ++k) {
          int idx = tid + k * 512, b = idx >> 9, c2 = idx & 511;
          if (((vx[k] ^ ex) & TAGMASK) == 0)
            *(unsigned*)(A_lds + (size_t)b * L1_STRIDE + 2 * c2) = pack32(vx[k]);
          else pendA |= 1u << k;
        }
#pragma unroll
        for (int k = 0; k < 16; ++k) {
          int idx = tid + k * 512, b = idx >> 8, c2 = idx & 255;
          if (((vh[k] ^ ex) & TAGMASK) == 0)
            *(unsigned*)(A_lds + (size_t)b * L1_STRIDE + 1024 + 2 * c2) = pack32(vh[k]);
          else pendB |= 1u << k;
        }
        if (pendA | pendB) {
          ull t0 = __builtin_amdgcn_s_memrealtime();
          while (pendA | pendB) {
#pragma unroll
            for (int k = 0; k < 32; ++k) if ((pendA >> k) & 1) {
              ull v = aload8(xw + tid + k * 512);
              if (((v ^ ex) & TAGMASK) == 0) {
                int idx = tid + k * 512, b = idx >> 9, c2 = idx & 511;
                *(unsigned*)(A_lds + (size_t)b * L1_STRIDE + 2 * c2) = pack32(v);
                pendA &= ~(1u << k);
              }
            }
#pragma unroll
            for (int k = 0; k < 16; ++k) if ((pendB >> k) & 1) {
              ull v = aload8(hw + tid + k * 512);
              if (((v ^ ex) & TAGMASK) == 0) {
                int idx = tid + k * 512, b = idx >> 8, c2 = idx & 255;
                *(unsigned*)(A_lds + (size_t)b * L1_STRIDE + 1024 + 2 * c2) = pack32(v);
                pendB &= ~(1u << k);
              }
            }
            if ((__builtin_amdgcn_s_memrealtime() - t0) > 100000000ULL ||
                __hip_atomic_load(abortf, __ATOMIC_RELAXED, __HIP_MEMORY_SCOPE_AGENT) != 0u) {
              __hip_atomic_store(abortf, 1u, __ATOMIC_RELAXED, __HIP_MEMORY_SCOPE_AGENT);
              sAbort = 1u;
              break;
            }
          }
        }
      } else if (l0act) {
        const ull* xw = (const ull*)XO + (size_t)s_rd * 16384 + d * 256;
        ull vx[16];
#pragma unroll
        for (int k = 0; k < 16; ++k) {
          int idx = tid + k * 512;
          vx[k] = aload8(xw + ((size_t)(idx >> 8) << 9) + (idx & 255));
        }
        unsigned pendA = 0;
#pragma unroll
        for (int k = 0; k < 16; ++k) {
          int idx = tid + k * 512, b = idx >> 8, c2 = idx & 255;
          if (((vx[k] ^ ex) & TAGMASK) == 0)
            *(unsigned*)(A_lds + (size_t)b * L0_STRIDE + 2 * c2) = pack32(vx[k]);
          else pendA |= 1u << k;
        }
        if (pendA) {
          ull t0 = __builtin_amdgcn_s_memrealtime();
          while (pendA) {
#pragma unroll
            for (int k = 0; k < 16; ++k) if ((pendA >> k) & 1) {
              int idx = tid + k * 512;
              ull v = aload8(xw + ((size_t)(idx >> 8) << 9) + (idx & 255));
              if (((v ^ ex) & TAGMASK) == 0) {
                int b = idx >> 8, c2 = idx & 255;
                *(unsigned*)(A_lds + (size_t)b * L0_STRIDE + 2 * c2) = pack32(v);
                pendA &= ~(1u << k);
              }
            }
            if ((__builtin_amdgcn_s_memrealtime() - t0) > 100000000ULL ||
                __hip_atomic_load(abortf, __ATOMIC_RELAXED, __HIP_MEMORY_SCOPE_AGENT) != 0u) {
              __hip_atomic_store(abortf, 1u, __ATOMIC_RELAXED, __HIP_MEMORY_SCOPE_AGENT);
              sAbort = 1u;
              break;
            }
          }
        }
      }
      __syncthreads();
      if (sAbort) { dead = true; break; }
      // consumer-progress flag (backpressure input), relaxed, no drain needed
      if (tid == 0 && (l1act || l0act))
        __hip_atomic_store(flags + (size_t)blk * 16, (unsigned)(p + 2),
                           __ATOMIC_RELAXED, __HIP_MEMORY_SCOPE_AGENT);

      // ---- MFMA from LDS x register weights ----
      if (w < 6) {
        if (l1act) {
          f32x4 p0 = {}, p1 = {}, q0 = {}, q1 = {};
          const unsigned short* al = A_lds + kh * 768 + hi8;
          if (g == 2 && kh == 1) {
#pragma unroll
            for (int i = 0; i < 8; ++i) {
              bf16x8 a0 = *reinterpret_cast<const bf16x8*>(al + ln * L1_STRIDE + i * 32);
              bf16x8 a1 = *reinterpret_cast<const bf16x8*>(al + (ln + 16) * L1_STRIDE + i * 32);
              p0 = MFMA16(a0, wreg[i], p0, 0, 0, 0);
              p1 = MFMA16(a1, wreg[i], p1, 0, 0, 0);
            }
#pragma unroll
            for (int i = 8; i < 24; ++i) {
              bf16x8 a0 = *reinterpret_cast<const bf16x8*>(al + ln * L1_STRIDE + i * 32);
              bf16x8 a1 = *reinterpret_cast<const bf16x8*>(al + (ln + 16) * L1_STRIDE + i * 32);
              q0 = MFMA16(a0, wreg[i], q0, 0, 0, 0);
              q1 = MFMA16(a1, wreg[i], q1, 0, 0, 0);
            }
            stile(5, p0, p1);
            stile(6, q0, q1);
          } else {
#pragma unroll
            for (int i = 0; i < 24; ++i) {
              bf16x8 a0 = *reinterpret_cast<const bf16x8*>(al + ln * L1_STRIDE + i * 32);
              bf16x8 a1 = *reinterpret_cast<const bf16x8*>(al + (ln + 16) * L1_STRIDE + i * 32);
              p0 = MFMA16(a0, wreg[i], p0, 0, 0, 0);
              p1 = MFMA16(a1, wreg[i], p1, 0, 0, 0);
            }
            stile((g < 2) ? g * 2 + kh : 4, p0, p1);
          }
        } else if (l0act) {
          f32x4 p0 = {}, p1 = {};
          const unsigned short* al = A_lds + kh * 256 + hi8;
#pragma unroll
          for (int i = 0; i < 8; ++i) {
            bf16x8 a0 = *reinterpret_cast<const bf16x8*>(al + ln * L0_STRIDE + i * 32);
            bf16x8 a1 = *reinterpret_cast<const bf16x8*>(al + (ln + 16) * L0_STRIDE + i * 32);
            p0 = MFMA16(a0, wreg[i], p0, 0, 0, 0);
            p1 = MFMA16(a1, wreg[i], p1, 0, 0, 0);
          }
          stile((g < 2) ? g * 2 + kh : 4 + kh, p0, p1);
        }
      }
      __syncthreads();

      // ---- nonlinearity + tagged state stores (no drain, no flag) ----
      unsigned tag = (unsigned)(p + 1);
      if (l1act && tid < 128) {
        int t_ = p - 1;
        int b = tid >> 2, j4 = (tid & 3) * 4;
        float hn[4];
#pragma unroll
        for (int k = 0; k < 4; ++k) {
          int jj = j4 + k;
          float r = sigm(pre[0][jj][b] + pre[1][jj][b] + bA[jj]);
          float z = sigm(pre[2][jj][b] + pre[3][jj][b] + bB[jj]);
          float nn = tanhf(pre[4][jj][b] + pre[5][jj][b] + bC[jj] +
                           r * (pre[6][jj][b] + bD[jj]));
          float h = hf[b][jj];
          float hnew = (1.f - z) * nn + z * h;
          hf[b][jj] = hnew;
          hn[k] = hnew;
        }
        ull* dH = (ull*)H1 + (((size_t)s_wr * 2 + d) * 32 + b) * 256 + ((j0 + j4) >> 1);
        astore8(dH, packpair(hn[0], hn[1], tag));
        astore8(dH + 1, packpair(hn[2], hn[3], tag));
        ull pk = (ull)f2b(hn[0]) | ((ull)f2b(hn[1]) << 16) |
                 ((ull)f2b(hn[2]) << 32) | ((ull)f2b(hn[3]) << 48);
        __builtin_nontemporal_store(
            pk, (ull*)(outs + ((size_t)t_ * 32 + b) * 1024 + d * 512 + j0 + j4));
      } else if (l0act && tid < 128) {
        int b = tid >> 2, j4 = (tid & 3) * 4;
        float hn[4];
#pragma unroll
        for (int k = 0; k < 4; ++k) {
          int jj = j4 + k;
          float gir = b2f((unsigned short)(gr >> (16 * k)));
          float giz = b2f((unsigned short)(gz2 >> (16 * k)));
          float gin = b2f((unsigned short)(gn2 >> (16 * k)));
          float r = sigm(gir + pre[0][jj][b] + pre[1][jj][b] + bA[jj]);
          float z = sigm(giz + pre[2][jj][b] + pre[3][jj][b] + bB[jj]);
          float nn = tanhf(gin + r * (pre[4][jj][b] + pre[5][jj][b] + bC[jj]));
          float h = hf[b][jj];
          float hnew = (1.f - z) * nn + z * h;
          hf[b][jj] = hnew;
          hn[k] = hnew;
        }
        ull* dX = (ull*)XO + ((size_t)s_wr * 32 + b) * 512 + d * 256 + ((j0 + j4) >> 1);
        astore8(dX, packpair(hn[0], hn[1], tag));
        astore8(dX + 1, packpair(hn[2], hn[3], tag));
      }
      // no barrier here: next phase's stage barrier provides the ordering
    }
  }

  // ---- final poll (consumers done) + scrub for replay safety ----
  if (!dead) {
    if (isL1) {
      if (w == 6) pollwait(lane < 32 ? d * 32 + lane : -1, 130u);
    } else {
      if (w == 6) pollwait(lane, 130u);
      else if (w == 7) pollwait(lane < 32 ? 64 + d * 32 + lane : -1, 129u);
    }
    __syncthreads();
  }
  if (tid < 128) {
    int b = tid >> 2, j4 = (tid & 3) * 4;
#pragma unroll
    for (int s = 0; s < 8; ++s) {
      ull* dst = isL1
          ? (ull*)H1 + (((size_t)s * 2 + d) * 32 + b) * 256 + ((j0 + j4) >> 1)
          : (ull*)XO + ((size_t)s * 32 + b) * 512 + d * 256 + ((j0 + j4) >> 1);
      astore8(dst, ~0ull);
      astore8(dst + 1, ~0ull);
    }
  }
}

// ---------------- log-softmax: partial reduce + subtract ----------------

__global__ __launch_bounds__(128) void lse_reduce(const float* __restrict__ pm,
                                                  const float* __restrict__ ps,
                                                  float* __restrict__ lsebuf) {
  int r = blockIdx.x * 128 + threadIdx.x;
  const float* pmr = pm + (size_t)r * 250;
  const float* psr = ps + (size_t)r * 250;
  float M = -1e30f, S = 0.f;
  for (int i = 0; i < 250; ++i) {
    float m2 = pmr[i], s2 = psr[i];
    if (m2 <= M) {
      S += s2 * __expf(m2 - M);
    } else {
      S = S * __expf(M - m2) + s2;
      M = m2;
    }
  }
  lsebuf[r] = M + __logf(S);
}

__global__ __launch_bounds__(256) void sub_lse(float* __restrict__ out,
                                               const float* __restrict__ lsebuf) {
  int row = blockIdx.x;
  float l = lsebuf[row];
  f32x4* rp = (f32x4*)(out + (size_t)row * Vv);
  for (int i = threadIdx.x; i < 8000; i += 256) {
    f32x4 v = __builtin_nontemporal_load(rp + i);
    v[0] -= l; v[1] -= l; v[2] -= l; v[3] -= l;
    __builtin_nontemporal_store(v, rp + i);
  }
}

// ---------------- host ----------------

extern "C" void kernel_launch(void* const* d_in, const int* in_sizes, int n_in,
                              void* d_out, int out_size, void* d_ws, size_t ws_size,
                              hipStream_t stream) {
  (void)in_sizes; (void)n_in; (void)out_size; (void)ws_size;
  const int*   target  = (const int*)  d_in[0];
  const float* context = (const float*)d_in[2];
  const float* table   = (const float*)d_in[3];
  const float* w_ih0   = (const float*)d_in[4];
  const float* w_hh0   = (const float*)d_in[5];
  const float* b_ih0   = (const float*)d_in[6];
  const float* b_hh0   = (const float*)d_in[7];
  const float* w_ih1   = (const float*)d_in[8];
  const float* w_hh1   = (const float*)d_in[9];
  const float* b_ih1   = (const float*)d_in[10];
  const float* b_hh1   = (const float*)d_in[11];
  const float* fc_w    = (const float*)d_in[12];
  const float* fc_b    = (const float*)d_in[13];
  float* out = (float*)d_out;

  uint8_t* ws = (uint8_t*)d_ws;
  size_t off = 0;
  auto alloc = [&](size_t bytes) {
    uint8_t* p = ws + off;
    off += (bytes + 255) & ~(size_t)255;
    return p;
  };
  unsigned*       bar   = (unsigned*)alloc(16384);
  unsigned*       XO    = (unsigned*)alloc((size_t)8 * 32 * 1024 * 4);
  unsigned*       H1    = (unsigned*)alloc((size_t)8 * 2 * 32 * 512 * 4);
  unsigned short* whh0b = (unsigned short*)alloc((size_t)1572864 * 2);
  unsigned short* w1cat = (unsigned short*)alloc((size_t)2 * 1536 * 1536 * 2);
  unsigned short* embb  = (unsigned short*)alloc((size_t)2097152 * 2);
  unsigned short* wih0b = (unsigned short*)alloc((size_t)1572864 * 2);
  unsigned short* gi0   = (unsigned short*)alloc((size_t)12582912 * 2);
  unsigned short* outsb = (unsigned short*)alloc((size_t)4194304 * 2);
  unsigned short* fcwb  = (unsigned short*)alloc((size_t)32768000 * 2);

  // partials + lse overlay gi0's region (dead after pers_kernel)
  float* pm     = (float*)gi0;
  float* ps     = pm + (size_t)4096 * 250;
  float* lsebuf = ps + (size_t)4096 * 250;

  static bool attr_done = false;
  if (!attr_done) {
    hipFuncSetAttribute(reinterpret_cast<const void*>(pers_kernel),
                        hipFuncAttributeMaxDynamicSharedMemorySize, 98816);
    attr_done = true;
  }

  // prep: all casts/packs/embeds + flag zeroing in one launch
  prep_all<<<dim3(8193), 256, 0, stream>>>(w_ih0, w_hh0, w_ih1, w_hh1, target, table,
                                           wih0b, whh0b, w1cat, embb, bar);

  // gi0 = emb * w_ih0^T + b_ih0  (bf16 out [d][4096][1536])
  gemm_nt<0><<<dim3(32, 12, 2), 256, 0, stream>>>(
      embb, wih0b, b_ih0, gi0, 512, 1536,
      (size_t)1536 * 512, (size_t)4096 * 1536, (size_t)1536, nullptr, nullptr);

  // recurrence (tag-in-data sync) + overlapped fc_w cast in helper blocks
  pers_kernel<<<dim3(256), 512, 98816, stream>>>(
      gi0, whh0b, w1cat, b_hh0, b_ih1, b_hh1, context, XO, H1, outsb, bar, fc_w, fcwb);

  // logits = outs * fc_w^T + fc_b  (row remap (s,b)->(b,s)) + LSE partials
  gemm_nt<1><<<dim3(32, 250, 1), 256, 0, stream>>>(
      outsb, fcwb, fc_b, out, 1024, Vv, 0, 0, 0, pm, ps);

  // log_softmax: reduce partials then subtract
  lse_reduce<<<dim3(32), 128, 0, stream>>>(pm, ps, lsebuf);
  sub_lse<<<dim3(4096), 256, 0, stream>>>(out, lsebuf);
}